// Round 1
// baseline (437.316 us; speedup 1.0000x reference)
//
#include <hip/hip_runtime.h>
#include <stdint.h>

// JAX >= 0.5 defaults jax_threefry_partitionable=True. If labels mismatch
// (absmax ~1-2), flip this to 0 (legacy split/iota stream).
#define JAX_PARTITIONABLE 1

static constexpr int B_   = 32;
static constexpr int NGT_ = 20;
static constexpr int H_   = 64;
static constexpr int W_   = 100;
static constexpr int A_   = 9;
static constexpr int HW_  = H_ * W_;        // 6400
static constexpr int T_   = HW_ * A_;       // 57600
static constexpr uint32_t NUMFG_ = 128u;
static constexpr uint32_t RPNBATCH_ = 256u;
static constexpr int OUT0_ = B_ * T_;           // 1843200 floats (labels)
static constexpr int OUTC_ = B_ * 4 * A_ * HW_; // 7372800 floats per weight/target tensor

// ---------------- Threefry-2x32-20 (bit-exact vs JAX) ----------------
struct TF2 { uint32_t a, b; };

__host__ __device__ constexpr uint32_t rotl32(uint32_t v, int r) {
  return (v << r) | (v >> (32 - r));
}

__host__ __device__ constexpr TF2 tf2x32(uint32_t k0, uint32_t k1,
                                         uint32_t x0, uint32_t x1) {
  uint32_t ks2 = k0 ^ k1 ^ 0x1BD11BDAu;
  x0 += k0; x1 += k1;
#define TFR_(r) x0 += x1; x1 = rotl32(x1, (r)); x1 ^= x0;
  TFR_(13) TFR_(15) TFR_(26) TFR_(6)
  x0 += k1;  x1 += ks2 + 1u;
  TFR_(17) TFR_(29) TFR_(16) TFR_(24)
  x0 += ks2; x1 += k0 + 2u;
  TFR_(13) TFR_(15) TFR_(26) TFR_(6)
  x0 += k0;  x1 += k1 + 3u;
  TFR_(17) TFR_(29) TFR_(16) TFR_(24)
  x0 += k1;  x1 += ks2 + 4u;
  TFR_(13) TFR_(15) TFR_(26) TFR_(6)
  x0 += ks2; x1 += k0 + 5u;
#undef TFR_
  return TF2{x0, x1};
}

// root key for jax.random.key(42) is (0, 42)
#if JAX_PARTITIONABLE
// fold-like split: key_i = threefry(root, (0, i))
static constexpr TF2 KFk = tf2x32(0u, 42u, 0u, 0u);
static constexpr TF2 KBk = tf2x32(0u, 42u, 0u, 1u);
static constexpr uint32_t KF0 = KFk.a, KF1 = KFk.b;
static constexpr uint32_t KB0 = KBk.a, KB1 = KBk.b;
#else
// original split: counts iota(4) -> pairs (0,2),(1,3); kf = (y0,y0'), kb = (y1,y1')
static constexpr TF2 R02 = tf2x32(0u, 42u, 0u, 2u);
static constexpr TF2 R13 = tf2x32(0u, 42u, 1u, 3u);
static constexpr uint32_t KF0 = R02.a, KF1 = R13.a;
static constexpr uint32_t KB0 = R02.b, KB1 = R13.b;
#endif

// 23-bit mantissa of uniform(key)[j]; ordering by this == ordering by u.
__device__ inline uint32_t mant23(uint32_t k0, uint32_t k1, uint32_t j) {
#if JAX_PARTITIONABLE
  TF2 r = tf2x32(k0, k1, 0u, j);          // 64-bit iota: hi=0, lo=j
  return (r.a ^ r.b) >> 9;
#else
  constexpr uint32_t HALF_ = (uint32_t)((uint64_t)B_ * T_ / 2); // 921600
  uint32_t lo = (j < HALF_) ? j : j - HALF_;
  TF2 r = tf2x32(k0, k1, lo, lo + HALF_);
  return ((j < HALF_) ? r.a : r.b) >> 9;
#endif
}

// ---------------- monotone float->uint key (order & equality preserving) ----
__device__ inline uint32_t fkey(float f) {
  uint32_t u = __float_as_uint(f);
  return (u & 0x80000000u) ? ~u : (u | 0x80000000u);
}
// fkey(+0.0f) == 0x80000000u  (the "gt_max == 0 -> 1e-5" sentinel)

// ---------------- base anchors (generate_anchors(), verified) ----------------
__constant__ float c_anc[9][4] = {
  { -84.f,  -40.f,  99.f,  55.f},
  {-176.f,  -88.f, 191.f, 103.f},
  {-360.f, -184.f, 375.f, 199.f},
  { -56.f,  -56.f,  71.f,  71.f},
  {-120.f, -120.f, 135.f, 135.f},
  {-248.f, -248.f, 263.f, 263.f},
  { -36.f,  -80.f,  51.f,  95.f},
  { -80.f, -168.f,  95.f, 183.f},
  {-168.f, -344.f, 183.f, 359.f},
};

// identical expression in all kernels; no FMA-contractable site -> bit-stable
__device__ inline float ov_one(float ax1, float ay1, float ax2, float ay2,
                               float aarea, bool inside,
                               float gx1, float gy1, float gx2, float gy2) {
  float gw = gx2 - gx1 + 1.0f;
  float gh = gy2 - gy1 + 1.0f;
  float garea = gw * gh;
  float iw = fminf(ax2, gx2) - fmaxf(ax1, gx1) + 1.0f;
  float ih = fminf(ay2, gy2) - fmaxf(ay1, gy1) + 1.0f;
  float inter = fmaxf(iw, 0.0f) * fmaxf(ih, 0.0f);
  float ua = aarea + garea - inter;
  float ov = inter / ua;
  if (gw == 1.0f && gh == 1.0f) ov = 0.0f;  // gt_zero
  if (!inside) ov = -2.0f;                  // ov_in
  return ov;
}

__device__ inline void anchor_of(int t, float& ax1, float& ay1, float& ax2, float& ay2) {
  const int a = t % A_;
  const int cell = t / A_;
  const int wx = cell % W_, hy = cell / W_;
  ax1 = c_anc[a][0] + wx * 16.0f;
  ay1 = c_anc[a][1] + hy * 16.0f;
  ax2 = c_anc[a][2] + wx * 16.0f;
  ay2 = c_anc[a][3] + hy * 16.0f;
}

// ---------------- K1: per-(b,g) max ov_in key ----------------
__global__ __launch_bounds__(256) void k1_gtmax(const float* __restrict__ gt,
                                                const float* __restrict__ im,
                                                uint32_t* __restrict__ gmax) {
  const int b = blockIdx.y;
  const int tid = threadIdx.x;
  const int t = blockIdx.x * 256 + tid;
  __shared__ float sgt[NGT_ * 5];
  __shared__ uint32_t skey[NGT_];
  if (tid < NGT_ * 5) sgt[tid] = gt[b * NGT_ * 5 + tid];
  if (tid < NGT_) skey[tid] = 0u;
  __syncthreads();

  float ax1, ay1, ax2, ay2;
  anchor_of(t, ax1, ay1, ax2, ay2);
  const float imh = im[0], imw = im[1];
  const bool inside = (ax1 >= 0.0f) && (ay1 >= 0.0f) && (ax2 < imw) && (ay2 < imh);
  const float aarea = (ax2 - ax1 + 1.0f) * (ay2 - ay1 + 1.0f);

  for (int g = 0; g < NGT_; ++g) {
    float ov = ov_one(ax1, ay1, ax2, ay2, aarea, inside,
                      sgt[g * 5], sgt[g * 5 + 1], sgt[g * 5 + 2], sgt[g * 5 + 3]);
    uint32_t k = fkey(ov);
    // wave-64 butterfly max, then one LDS atomic per wave
    for (int d = 1; d < 64; d <<= 1) {
      uint32_t o = (uint32_t)__shfl_xor((int)k, d, 64);
      k = (o > k) ? o : k;
    }
    if ((tid & 63) == 0) atomicMax(&skey[g], k);
  }
  __syncthreads();
  if (tid < NGT_) atomicMax(&gmax[b * 32 + tid], skey[tid]);
}

// ---------------- K2: pre-sampling labels + fg/bg counts ----------------
__global__ __launch_bounds__(256) void k2_label(const float* __restrict__ gt,
                                                const float* __restrict__ im,
                                                const uint32_t* __restrict__ gmax,
                                                int8_t* __restrict__ labels,
                                                uint32_t* __restrict__ counts) {
  const int b = blockIdx.y;
  const int tid = threadIdx.x;
  const int t = blockIdx.x * 256 + tid;
  __shared__ float sgt[NGT_ * 5];
  __shared__ uint32_t skey[NGT_];
  __shared__ uint32_t cfg, cbg;
  if (tid < NGT_ * 5) sgt[tid] = gt[b * NGT_ * 5 + tid];
  if (tid < NGT_) skey[tid] = gmax[b * 32 + tid];
  if (tid == 0) { cfg = 0u; cbg = 0u; }
  __syncthreads();

  float ax1, ay1, ax2, ay2;
  anchor_of(t, ax1, ay1, ax2, ay2);
  const float imh = im[0], imw = im[1];
  const bool inside = (ax1 >= 0.0f) && (ay1 >= 0.0f) && (ax2 < imw) && (ay2 < imh);
  const float aarea = (ax2 - ax1 + 1.0f) * (ay2 - ay1 + 1.0f);

  float maxov = -1e30f;
  bool haskeep = false;
  for (int g = 0; g < NGT_; ++g) {
    float ov = ov_one(ax1, ay1, ax2, ay2, aarea, inside,
                      sgt[g * 5], sgt[g * 5 + 1], sgt[g * 5 + 2], sgt[g * 5 + 3]);
    uint32_t gk = skey[g];
    if (fkey(ov) == gk && gk != 0x80000000u) haskeep = true;  // gt_max==0 -> 1e-5, never matches
    maxov = fmaxf(maxov, ov);
  }
  int lab = -1;
  if (maxov < 0.3f) lab = 0;
  if (haskeep) lab = 1;
  if (maxov >= 0.7f) lab = 1;
  if (!inside) lab = -1;
  labels[(size_t)b * T_ + t] = (int8_t)lab;

  unsigned long long m1 = __ballot(lab == 1);
  unsigned long long m0 = __ballot(lab == 0);
  if ((tid & 63) == 0) {
    if (m1) atomicAdd(&cfg, (uint32_t)__popcll(m1));
    if (m0) atomicAdd(&cbg, (uint32_t)__popcll(m0));
  }
  __syncthreads();
  if (tid == 0) {
    if (cfg) atomicAdd(&counts[b * 2 + 0], cfg);
    if (cbg) atomicAdd(&counts[b * 2 + 1], cbg);
  }
}

// ---------------- K3: per-(row,class) K-th smallest (m, t) selection ------
__device__ inline void find_kth(uint32_t* hist, int n, uint32_t target, int tid,
                                uint32_t* wsum, uint32_t* res) {
  const int C = n >> 8;  // n / 256
  const int base = tid * C;
  uint32_t s = 0;
  for (int i = 0; i < C; ++i) s += hist[base + i];
  uint32_t v = s;
  for (int d = 1; d < 64; d <<= 1) {
    uint32_t u = (uint32_t)__shfl_up((int)v, d, 64);
    if ((tid & 63) >= d) v += u;
  }
  if ((tid & 63) == 63) wsum[tid >> 6] = v;
  __syncthreads();
  uint32_t woff = 0;
  for (int w2 = 0; w2 < (tid >> 6); ++w2) woff += wsum[w2];
  uint32_t c = woff + v - s;   // total count in buckets before this chunk
  for (int i = 0; i < C; ++i) {
    uint32_t h = hist[base + i];
    if (h != 0u && target >= c && target < c + h) {
      res[0] = (uint32_t)(base + i);
      res[1] = c;
    }
    c += h;
  }
  __syncthreads();
}

__global__ __launch_bounds__(256) void k3_select(const int8_t* __restrict__ labels,
                                                 const uint32_t* __restrict__ counts,
                                                 uint32_t* __restrict__ sel) {
  const int b = blockIdx.x >> 1;
  const int cls = blockIdx.x & 1;  // 0 = fg, 1 = bg
  const int tid = threadIdx.x;
  __shared__ uint32_t hist[4096];
  __shared__ uint32_t wsum[4];
  __shared__ uint32_t res[2];
  __shared__ uint32_t lcnt;

  const uint32_t cf = counts[b * 2 + 0];
  const uint32_t cb = counts[b * 2 + 1];
  const uint32_t fgk = cf < NUMFG_ ? cf : NUMFG_;
  const uint32_t K = (cls == 0) ? NUMFG_ : RPNBATCH_ - fgk;
  const uint32_t cnt = (cls == 0) ? cf : cb;
  if (cnt <= K) {  // keep everything
    if (tid == 0) { sel[b * 4 + cls * 2] = 0xFFFFFFFFu; sel[b * 4 + cls * 2 + 1] = 0xFFFFFFFFu; }
    return;
  }
  const int8_t want = (cls == 0) ? (int8_t)1 : (int8_t)0;
  const uint32_t k0 = (cls == 0) ? KF0 : KB0;
  const uint32_t k1 = (cls == 0) ? KF1 : KB1;
  const uint32_t jbase = (uint32_t)b * (uint32_t)T_;
  const int8_t* lrow = labels + (size_t)b * T_;

  // level 1: histogram of top 11 bits of 23-bit mantissa
  for (int i = tid; i < 2048; i += 256) hist[i] = 0u;
  __syncthreads();
  for (int t = tid; t < T_; t += 256) {
    if (lrow[t] == want) {
      uint32_t m = mant23(k0, k1, jbase + (uint32_t)t);
      atomicAdd(&hist[m >> 12], 1u);
    }
  }
  __syncthreads();
  find_kth(hist, 2048, K - 1u, tid, wsum, res);
  const uint32_t b1 = res[0], cb1 = res[1];
  __syncthreads();

  // level 2: low 12 bits within bucket b1
  for (int i = tid; i < 4096; i += 256) hist[i] = 0u;
  __syncthreads();
  for (int t = tid; t < T_; t += 256) {
    if (lrow[t] == want) {
      uint32_t m = mant23(k0, k1, jbase + (uint32_t)t);
      if ((m >> 12) == b1) atomicAdd(&hist[m & 0xFFFu], 1u);
    }
  }
  __syncthreads();
  find_kth(hist, 4096, K - 1u - cb1, tid, wsum, res);
  const uint32_t b2 = res[0], cb2 = res[1];
  const uint32_t Mstar = (b1 << 12) | b2;
  const uint32_t need = K - cb1 - cb2;  // how many m==Mstar to keep (>=1)
  const uint32_t cnteq = hist[b2];
  uint32_t tstar = 0xFFFFFFFFu;
  if (need < cnteq) {  // tie-break on anchor index (stable argsort order)
    if (tid == 0) lcnt = 0u;
    __syncthreads();
    for (int t = tid; t < T_; t += 256) {
      if (lrow[t] == want && mant23(k0, k1, jbase + (uint32_t)t) == Mstar) {
        uint32_t p = atomicAdd(&lcnt, 1u);
        if (p < 4096u) hist[p] = (uint32_t)t;
      }
    }
    __syncthreads();
    if (tid == 0) {
      uint32_t n = lcnt < 4096u ? lcnt : 4096u;
      uint32_t prev = 0u;
      for (uint32_t kk = 0; kk < need; ++kk) {  // need-th smallest index
        uint32_t mn = 0xFFFFFFFFu;
        for (uint32_t i2 = 0; i2 < n; ++i2) {
          uint32_t vv = hist[i2];
          if ((kk == 0u || vv > prev) && vv < mn) mn = vv;
        }
        prev = mn;
      }
      tstar = prev;
    }
  }
  if (tid == 0) { sel[b * 4 + cls * 2] = Mstar; sel[b * 4 + cls * 2 + 1] = tstar; }
}

// ---------------- K4: finalize labels, targets, weights; write outputs ----
__global__ __launch_bounds__(256) void k4_final(const float* __restrict__ gt,
                                                const float* __restrict__ im,
                                                const int8_t* __restrict__ labels,
                                                const uint32_t* __restrict__ counts,
                                                const uint32_t* __restrict__ sel,
                                                float* __restrict__ out) {
  const int b = blockIdx.y;
  const int tid = threadIdx.x;
  const int i = blockIdx.x * 256 + tid;  // i = a*HW + cell (channel-major for coalescing)
  __shared__ float sgt[NGT_ * 5];
  if (tid < NGT_ * 5) sgt[tid] = gt[b * NGT_ * 5 + tid];
  __syncthreads();

  const int a = i / HW_;
  const int cell = i % HW_;
  const int t = cell * A_ + a;  // original anchor index

  float ax1, ay1, ax2, ay2;
  anchor_of(t, ax1, ay1, ax2, ay2);
  const float imh = im[0], imw = im[1];
  const bool inside = (ax1 >= 0.0f) && (ay1 >= 0.0f) && (ax2 < imw) && (ay2 < imh);
  const float aarea = (ax2 - ax1 + 1.0f) * (ay2 - ay1 + 1.0f);

  int lab = labels[(size_t)b * T_ + t];
  const uint32_t j = (uint32_t)b * (uint32_t)T_ + (uint32_t)t;
  if (lab == 1) {
    uint32_t m = mant23(KF0, KF1, j);
    uint32_t Ms = sel[b * 4 + 0], ts = sel[b * 4 + 1];
    if (!(m < Ms || (m == Ms && (uint32_t)t <= ts))) lab = -1;
  } else if (lab == 0) {
    uint32_t m = mant23(KB0, KB1, j);
    uint32_t Ms = sel[b * 4 + 2], ts = sel[b * 4 + 3];
    if (!(m < Ms || (m == Ms && (uint32_t)t <= ts))) lab = -1;
  }

  const uint32_t cf = counts[b * 2 + 0];
  const uint32_t cbn = counts[b * 2 + 1];
  const uint32_t fgk = cf < NUMFG_ ? cf : NUMFG_;
  const uint32_t nbg = RPNBATCH_ - fgk;
  const uint32_t bgk = cbn < nbg ? cbn : nbg;
  const float uw = 1.0f / (float)(fgk + bgk);

  float tg0 = 0.f, tg1 = 0.f, tg2 = 0.f, tg3 = 0.f;
  if (inside) {
    float best = -1e30f;
    int bg_ = 0;
    for (int g = 0; g < NGT_; ++g) {
      float ov = ov_one(ax1, ay1, ax2, ay2, aarea, inside,
                        sgt[g * 5], sgt[g * 5 + 1], sgt[g * 5 + 2], sgt[g * 5 + 3]);
      if (ov > best) { best = ov; bg_ = g; }  // first-max (jnp.argmax)
    }
    const float gx1 = sgt[bg_ * 5], gy1 = sgt[bg_ * 5 + 1];
    const float gx2 = sgt[bg_ * 5 + 2], gy2 = sgt[bg_ * 5 + 3];
    const float ew = ax2 - ax1 + 1.0f, eh = ay2 - ay1 + 1.0f;
    const float ecx = ax1 + 0.5f * ew, ecy = ay1 + 0.5f * eh;
    const float gw = gx2 - gx1 + 1.0f, gh = gy2 - gy1 + 1.0f;
    const float gcx = gx1 + 0.5f * gw, gcy = gy1 + 0.5f * gh;
    tg0 = (gcx - ecx) / ew;
    tg1 = (gcy - ecy) / eh;
    tg2 = logf(gw / ew);
    tg3 = logf(gh / eh);
  }
  const float inw = (lab == 1) ? 1.0f : 0.0f;
  const float oww = (lab == 1 || lab == 0) ? uw : 0.0f;

  // labels_o: (B, 1, A*H, W) == [b][a][h][w]
  out[(size_t)b * T_ + (size_t)a * HW_ + cell] = (float)lab;
  // targets / in_w / out_w: (B, 4A, H, W), channel c = a*4 + k
  const size_t ch = ((size_t)b * 36 + (size_t)a * 4) * HW_ + cell;
  float* o1 = out + OUT0_;
  o1[ch] = tg0; o1[ch + HW_] = tg1; o1[ch + 2 * HW_] = tg2; o1[ch + 3 * HW_] = tg3;
  float* o2 = o1 + OUTC_;
  o2[ch] = inw; o2[ch + HW_] = inw; o2[ch + 2 * HW_] = inw; o2[ch + 3 * HW_] = inw;
  float* o3 = o2 + OUTC_;
  o3[ch] = oww; o3[ch + HW_] = oww; o3[ch + 2 * HW_] = oww; o3[ch + 3 * HW_] = oww;
}

extern "C" void kernel_launch(void* const* d_in, const int* in_sizes, int n_in,
                              void* d_out, int out_size, void* d_ws, size_t ws_size,
                              hipStream_t stream) {
  (void)in_sizes; (void)n_in; (void)out_size; (void)ws_size;
  const float* gt = (const float*)d_in[1];   // (32,20,5)
  const float* im = (const float*)d_in[2];   // (32,3)
  float* out = (float*)d_out;

  uint8_t* ws = (uint8_t*)d_ws;
  uint32_t* gmax = (uint32_t*)ws;                 // 32*32 u32  (offset 0, 4096 B)
  uint32_t* counts = (uint32_t*)(ws + 4096);      // 32*2  u32  (256 B)
  uint32_t* sel = (uint32_t*)(ws + 4352);         // 32*4  u32  (512 B)
  int8_t* labels = (int8_t*)(ws + 4864);          // 32*57600 i8 (~1.8 MB)

  (void)hipMemsetAsync(ws, 0, 4864, stream);  // zero gmax + counts (+sel)

  dim3 blk(256);
  dim3 grd(T_ / 256, B_);  // 225 x 32, exact
  k1_gtmax<<<grd, blk, 0, stream>>>(gt, im, gmax);
  k2_label<<<grd, blk, 0, stream>>>(gt, im, gmax, labels, counts);
  k3_select<<<dim3(B_ * 2), blk, 0, stream>>>(labels, counts, sel);
  k4_final<<<grd, blk, 0, stream>>>(gt, im, labels, counts, sel, out);
}

// Round 2
// 368.743 us; speedup vs baseline: 1.1860x; 1.1860x over previous
//
#include <hip/hip_runtime.h>
#include <stdint.h>

// JAX >= 0.5 defaults jax_threefry_partitionable=True (verified R1: absmax 0.0).
#define JAX_PARTITIONABLE 1

static constexpr int B_   = 32;
static constexpr int NGT_ = 20;
static constexpr int H_   = 64;
static constexpr int W_   = 100;
static constexpr int A_   = 9;
static constexpr int HW_  = H_ * W_;        // 6400
static constexpr int T_   = HW_ * A_;       // 57600
static constexpr uint32_t NUMFG_ = 128u;
static constexpr uint32_t RPNBATCH_ = 256u;
static constexpr int OUT0_ = B_ * T_;           // labels floats
static constexpr int OUTC_ = B_ * 4 * A_ * HW_; // per targets/in_w/out_w tensor

// ---------------- Threefry-2x32-20 (bit-exact vs JAX) ----------------
struct TF2 { uint32_t a, b; };

__host__ __device__ constexpr uint32_t rotl32(uint32_t v, int r) {
  return (v << r) | (v >> (32 - r));
}

__host__ __device__ constexpr TF2 tf2x32(uint32_t k0, uint32_t k1,
                                         uint32_t x0, uint32_t x1) {
  uint32_t ks2 = k0 ^ k1 ^ 0x1BD11BDAu;
  x0 += k0; x1 += k1;
#define TFR_(r) x0 += x1; x1 = rotl32(x1, (r)); x1 ^= x0;
  TFR_(13) TFR_(15) TFR_(26) TFR_(6)
  x0 += k1;  x1 += ks2 + 1u;
  TFR_(17) TFR_(29) TFR_(16) TFR_(24)
  x0 += ks2; x1 += k0 + 2u;
  TFR_(13) TFR_(15) TFR_(26) TFR_(6)
  x0 += k0;  x1 += k1 + 3u;
  TFR_(17) TFR_(29) TFR_(16) TFR_(24)
  x0 += k1;  x1 += ks2 + 4u;
  TFR_(13) TFR_(15) TFR_(26) TFR_(6)
  x0 += ks2; x1 += k0 + 5u;
#undef TFR_
  return TF2{x0, x1};
}

#if JAX_PARTITIONABLE
static constexpr TF2 KFk = tf2x32(0u, 42u, 0u, 0u);
static constexpr TF2 KBk = tf2x32(0u, 42u, 0u, 1u);
static constexpr uint32_t KF0 = KFk.a, KF1 = KFk.b;
static constexpr uint32_t KB0 = KBk.a, KB1 = KBk.b;
#else
static constexpr TF2 R02 = tf2x32(0u, 42u, 0u, 2u);
static constexpr TF2 R13 = tf2x32(0u, 42u, 1u, 3u);
static constexpr uint32_t KF0 = R02.a, KF1 = R13.a;
static constexpr uint32_t KB0 = R02.b, KB1 = R13.b;
#endif

__device__ inline uint32_t mant23(uint32_t k0, uint32_t k1, uint32_t j) {
#if JAX_PARTITIONABLE
  TF2 r = tf2x32(k0, k1, 0u, j);
  return (r.a ^ r.b) >> 9;
#else
  constexpr uint32_t HALF_ = (uint32_t)((uint64_t)B_ * T_ / 2);
  uint32_t lo = (j < HALF_) ? j : j - HALF_;
  TF2 r = tf2x32(k0, k1, lo, lo + HALF_);
  return ((j < HALF_) ? r.a : r.b) >> 9;
#endif
}

// monotone float->uint key (order & equality preserving); fkey(+0) = 0x80000000
__device__ inline uint32_t fkey(float f) {
  uint32_t u = __float_as_uint(f);
  return (u & 0x80000000u) ? ~u : (u | 0x80000000u);
}

__constant__ float c_anc[9][4] = {
  { -84.f,  -40.f,  99.f,  55.f},
  {-176.f,  -88.f, 191.f, 103.f},
  {-360.f, -184.f, 375.f, 199.f},
  { -56.f,  -56.f,  71.f,  71.f},
  {-120.f, -120.f, 135.f, 135.f},
  {-248.f, -248.f, 263.f, 263.f},
  { -36.f,  -80.f,  51.f,  95.f},
  { -80.f, -168.f,  95.f, 183.f},
  {-168.f, -344.f, 183.f, 359.f},
};

// IOU for an INSIDE anchor vs a NON-ZERO gt. contract(off) => bitwise == numpy.
__device__ inline float ov_inside(float ax1, float ay1, float ax2, float ay2,
                                  float aarea,
                                  float gx1, float gy1, float gx2, float gy2) {
#pragma clang fp contract(off)
  float gw = gx2 - gx1 + 1.0f;
  float gh = gy2 - gy1 + 1.0f;
  float garea = gw * gh;
  float iw = fminf(ax2, gx2) - fmaxf(ax1, gx1) + 1.0f;
  float ih = fminf(ay2, gy2) - fmaxf(ay1, gy1) + 1.0f;
  float inter = fmaxf(iw, 0.0f) * fmaxf(ih, 0.0f);
  float ua = aarea + garea - inter;
  return inter / ua;
}

// a-major index i = a*HW + cell; anchor coords for (a, cell)
__device__ inline void anchor_of_ac(int a, int cell,
                                    float& ax1, float& ay1, float& ax2, float& ay2) {
#pragma clang fp contract(off)
  const int wx = cell % W_, hy = cell / W_;
  ax1 = c_anc[a][0] + wx * 16.0f;
  ay1 = c_anc[a][1] + hy * 16.0f;
  ax2 = c_anc[a][2] + wx * 16.0f;
  ay2 = c_anc[a][3] + hy * 16.0f;
}

// ---------------- K1: per-(b,g) max IOU key over inside anchors ----------
__global__ __launch_bounds__(256) void k1_gtmax(const float* __restrict__ gt,
                                                const float* __restrict__ im,
                                                uint32_t* __restrict__ gmax) {
#pragma clang fp contract(off)
  const int b = blockIdx.y;
  const int tid = threadIdx.x;
  const int i = blockIdx.x * 256 + tid;
  __shared__ float sgt[NGT_ * 5];
  __shared__ uint32_t skey[NGT_];
  if (tid < NGT_ * 5) sgt[tid] = gt[b * NGT_ * 5 + tid];
  if (tid < NGT_) skey[tid] = 0u;
  __syncthreads();

  const int a = i / HW_, cell = i % HW_;
  float ax1, ay1, ax2, ay2;
  anchor_of_ac(a, cell, ax1, ay1, ax2, ay2);
  const float imh = im[0], imw = im[1];
  const bool inside = (ax1 >= 0.0f) && (ay1 >= 0.0f) && (ax2 < imw) && (ay2 < imh);
  const float aarea = (ax2 - ax1 + 1.0f) * (ay2 - ay1 + 1.0f);

  if (__ballot(inside) != 0ull) {
    for (int g = 0; g < NGT_; ++g) {
      const float gx1 = sgt[g * 5], gy1 = sgt[g * 5 + 1];
      const float gx2 = sgt[g * 5 + 2], gy2 = sgt[g * 5 + 3];
      if (gx2 - gx1 + 1.0f == 1.0f && gy2 - gy1 + 1.0f == 1.0f) continue;  // zero gt
      float ov = ov_inside(ax1, ay1, ax2, ay2, aarea, gx1, gy1, gx2, gy2);
      uint32_t k = inside ? fkey(ov) : 0u;  // outside contributes -2 < any inside ov
      for (int d = 1; d < 64; d <<= 1) {
        uint32_t o = (uint32_t)__shfl_xor((int)k, d, 64);
        k = (o > k) ? o : k;
      }
      if ((tid & 63) == 0) atomicMax(&skey[g], k);
    }
  }
  __syncthreads();
  if (tid < NGT_) atomicMax(&gmax[b * 32 + tid], skey[tid]);
}

// ---------------- K2: labels + argmax + compacted candidate lists --------
__global__ __launch_bounds__(256) void k2_label(const float* __restrict__ gt,
                                                const float* __restrict__ im,
                                                const uint32_t* __restrict__ gmax,
                                                int8_t* __restrict__ labels,
                                                int8_t* __restrict__ argmax8,
                                                uint32_t* __restrict__ cnt,
                                                uint32_t* __restrict__ cand) {
#pragma clang fp contract(off)
  const int b = blockIdx.y;
  const int tid = threadIdx.x;
  const int i = blockIdx.x * 256 + tid;
  __shared__ float sgt[NGT_ * 5];
  __shared__ uint32_t skey[NGT_];
  if (tid < NGT_ * 5) sgt[tid] = gt[b * NGT_ * 5 + tid];
  if (tid < NGT_) skey[tid] = gmax[b * 32 + tid];
  __syncthreads();

  const int a = i / HW_, cell = i % HW_;
  const int t = cell * A_ + a;  // original anchor index (for threefry j)
  float ax1, ay1, ax2, ay2;
  anchor_of_ac(a, cell, ax1, ay1, ax2, ay2);
  const float imh = im[0], imw = im[1];
  const bool inside = (ax1 >= 0.0f) && (ay1 >= 0.0f) && (ax2 < imw) && (ay2 < imh);
  const float aarea = (ax2 - ax1 + 1.0f) * (ay2 - ay1 + 1.0f);

  float maxov = -2.0f;
  bool haskeep = false;
  int bg_ = 0;
  if (__ballot(inside) != 0ull) {
    float best = -1e30f;
    for (int g = 0; g < NGT_; ++g) {
      const float gx1 = sgt[g * 5], gy1 = sgt[g * 5 + 1];
      const float gx2 = sgt[g * 5 + 2], gy2 = sgt[g * 5 + 3];
      if (gx2 - gx1 + 1.0f == 1.0f && gy2 - gy1 + 1.0f == 1.0f) continue;  // zero gt
      float ov = ov_inside(ax1, ay1, ax2, ay2, aarea, gx1, gy1, gx2, gy2);
      uint32_t gk = skey[g];
      if (inside && fkey(ov) == gk && gk != 0x80000000u) haskeep = true;
      if (ov > best) { best = ov; bg_ = g; }  // first-max == jnp.argmax
    }
    if (inside) maxov = fmaxf(best, 0.0f);  // zero-gt columns contribute 0
    else bg_ = 0;
  }
  int lab = -1;
  if (inside) {
    if (maxov < 0.3f) lab = 0;
    if (haskeep) lab = 1;
    if (maxov >= 0.7f) lab = 1;
  }
  labels[(size_t)b * T_ + i] = (int8_t)lab;     // a-major storage
  argmax8[(size_t)b * T_ + i] = (int8_t)bg_;

  uint32_t m = 0;
  if (lab >= 0)
    m = mant23(lab ? KF0 : KB0, lab ? KF1 : KB1, (uint32_t)(b * T_ + t));

  const int lane = tid & 63;
  {  // fg append
    unsigned long long mk = __ballot(lab == 1);
    if (mk) {
      int lead = __ffsll((long long)mk) - 1;
      uint32_t base2 = 0;
      if (lane == lead) base2 = atomicAdd(&cnt[b * 2 + 0], (uint32_t)__popcll(mk));
      base2 = (uint32_t)__shfl((int)base2, lead, 64);
      if (lab == 1) {
        uint32_t off = (uint32_t)__popcll(mk & ((1ull << lane) - 1ull));
        cand[((size_t)0 * B_ + b) * T_ + base2 + off] = m;
      }
    }
  }
  {  // bg append
    unsigned long long mk = __ballot(lab == 0);
    if (mk) {
      int lead = __ffsll((long long)mk) - 1;
      uint32_t base2 = 0;
      if (lane == lead) base2 = atomicAdd(&cnt[b * 2 + 1], (uint32_t)__popcll(mk));
      base2 = (uint32_t)__shfl((int)base2, lead, 64);
      if (lab == 0) {
        uint32_t off = (uint32_t)__popcll(mk & ((1ull << lane) - 1ull));
        cand[((size_t)1 * B_ + b) * T_ + base2 + off] = m;
      }
    }
  }
}

// ---------------- K3: K-th smallest over compacted candidates ------------
__device__ inline void find_kth1024(uint32_t* hist, int n, uint32_t target, int tid,
                                    uint32_t* wsum, uint32_t* res) {
  const int C = n >> 10;  // n / 1024
  const int base = tid * C;
  uint32_t s = 0;
  for (int i = 0; i < C; ++i) s += hist[base + i];
  uint32_t v = s;
  for (int d = 1; d < 64; d <<= 1) {
    uint32_t u = (uint32_t)__shfl_up((int)v, d, 64);
    if ((tid & 63) >= d) v += u;
  }
  const int wv = tid >> 6;
  if ((tid & 63) == 63) wsum[wv] = v;
  __syncthreads();
  uint32_t woff = 0;
  for (int w2 = 0; w2 < wv; ++w2) woff += wsum[w2];
  uint32_t c = woff + v - s;
  for (int i = 0; i < C; ++i) {
    uint32_t h = hist[base + i];
    if (h != 0u && target >= c && target < c + h) {
      res[0] = (uint32_t)(base + i);
      res[1] = c;
    }
    c += h;
  }
  __syncthreads();
}

__global__ __launch_bounds__(1024) void k3_select(const int8_t* __restrict__ labels,
                                                  const uint32_t* __restrict__ cnt,
                                                  const uint32_t* __restrict__ cand,
                                                  uint32_t* __restrict__ sel) {
  const int b = blockIdx.x >> 1;
  const int cls = blockIdx.x & 1;  // 0=fg, 1=bg
  const int tid = threadIdx.x;
  __shared__ uint32_t hist[4096];
  __shared__ uint32_t wsum[16];
  __shared__ uint32_t res[2];
  __shared__ uint32_t lcnt;

  const uint32_t cf = cnt[b * 2 + 0];
  const uint32_t cb = cnt[b * 2 + 1];
  const uint32_t fgk = cf < NUMFG_ ? cf : NUMFG_;
  const uint32_t K = (cls == 0) ? NUMFG_ : RPNBATCH_ - fgk;
  const uint32_t n = (cls == 0) ? cf : cb;
  if (n <= K) {
    if (tid == 0) { sel[b * 4 + cls * 2] = 0xFFFFFFFFu; sel[b * 4 + cls * 2 + 1] = 0xFFFFFFFFu; }
    return;
  }
  const uint32_t* list = cand + ((size_t)cls * B_ + b) * T_;

  // level 1: top 11 bits
  for (int i = tid; i < 2048; i += 1024) hist[i] = 0u;
  __syncthreads();
  for (uint32_t i = tid; i < n; i += 1024) atomicAdd(&hist[list[i] >> 12], 1u);
  __syncthreads();
  find_kth1024(hist, 2048, K - 1u, tid, wsum, res);
  const uint32_t b1 = res[0], cb1 = res[1];
  __syncthreads();

  // level 2: low 12 bits within bucket b1
  for (int i = tid; i < 4096; i += 1024) hist[i] = 0u;
  __syncthreads();
  for (uint32_t i = tid; i < n; i += 1024) {
    uint32_t m = list[i];
    if ((m >> 12) == b1) atomicAdd(&hist[m & 0xFFFu], 1u);
  }
  __syncthreads();
  find_kth1024(hist, 4096, K - 1u - cb1, tid, wsum, res);
  const uint32_t b2 = res[0], cb2 = res[1];
  const uint32_t Mstar = (b1 << 12) | b2;
  const uint32_t need = K - cb1 - cb2;
  const uint32_t cnteq = hist[b2];
  __syncthreads();

  uint32_t tstar = 0xFFFFFFFFu;
  if (need < cnteq) {  // tie on mantissa straddles boundary: break on anchor index
    const int8_t want = (cls == 0) ? (int8_t)1 : (int8_t)0;
    const uint32_t k0 = (cls == 0) ? KF0 : KB0;
    const uint32_t k1 = (cls == 0) ? KF1 : KB1;
    const int8_t* lrow = labels + (size_t)b * T_;
    if (tid == 0) lcnt = 0u;
    __syncthreads();
    for (int s = tid; s < T_; s += 1024) {
      if (lrow[s] == want) {
        int aa = s / HW_, cc = s % HW_;
        uint32_t t = (uint32_t)(cc * A_ + aa);
        if (mant23(k0, k1, (uint32_t)b * (uint32_t)T_ + t) == Mstar) {
          uint32_t p = atomicAdd(&lcnt, 1u);
          if (p < 4096u) hist[p] = t;
        }
      }
    }
    __syncthreads();
    if (tid == 0) {
      uint32_t nn = lcnt < 4096u ? lcnt : 4096u;
      uint32_t prev = 0u;
      for (uint32_t kk = 0; kk < need; ++kk) {
        uint32_t mn = 0xFFFFFFFFu;
        for (uint32_t i2 = 0; i2 < nn; ++i2) {
          uint32_t vv = hist[i2];
          if ((kk == 0u || vv > prev) && vv < mn) mn = vv;
        }
        prev = mn;
      }
      tstar = prev;
    }
  }
  if (tid == 0) { sel[b * 4 + cls * 2] = Mstar; sel[b * 4 + cls * 2 + 1] = tstar; }
}

// ---------------- K4: finalize + write all outputs -----------------------
__global__ __launch_bounds__(256) void k4_final(const float* __restrict__ gt,
                                                const float* __restrict__ im,
                                                const int8_t* __restrict__ labels,
                                                const int8_t* __restrict__ argmax8,
                                                const uint32_t* __restrict__ cnt,
                                                const uint32_t* __restrict__ sel,
                                                float* __restrict__ out) {
#pragma clang fp contract(off)
  const int b = blockIdx.y;
  const int tid = threadIdx.x;
  const int i = blockIdx.x * 256 + tid;
  __shared__ float sgt[NGT_ * 5];
  if (tid < NGT_ * 5) sgt[tid] = gt[b * NGT_ * 5 + tid];
  __syncthreads();

  const int a = i / HW_, cell = i % HW_;
  const int t = cell * A_ + a;
  float ax1, ay1, ax2, ay2;
  anchor_of_ac(a, cell, ax1, ay1, ax2, ay2);
  const float imh = im[0], imw = im[1];
  const bool inside = (ax1 >= 0.0f) && (ay1 >= 0.0f) && (ax2 < imw) && (ay2 < imh);

  int lab = labels[(size_t)b * T_ + i];
  const uint32_t j = (uint32_t)(b * T_ + t);
  if (lab == 1) {
    uint32_t m = mant23(KF0, KF1, j);
    uint32_t Ms = sel[b * 4 + 0], ts = sel[b * 4 + 1];
    if (!(m < Ms || (m == Ms && (uint32_t)t <= ts))) lab = -1;
  } else if (lab == 0) {
    uint32_t m = mant23(KB0, KB1, j);
    uint32_t Ms = sel[b * 4 + 2], ts = sel[b * 4 + 3];
    if (!(m < Ms || (m == Ms && (uint32_t)t <= ts))) lab = -1;
  }

  const uint32_t cf = cnt[b * 2 + 0];
  const uint32_t cbn = cnt[b * 2 + 1];
  const uint32_t fgk = cf < NUMFG_ ? cf : NUMFG_;
  const uint32_t nbg = RPNBATCH_ - fgk;
  const uint32_t bgk = cbn < nbg ? cbn : nbg;
  const float uw = 1.0f / (float)(fgk + bgk);

  float tg0 = 0.f, tg1 = 0.f, tg2 = 0.f, tg3 = 0.f;
  if (inside) {
    const int bg_ = argmax8[(size_t)b * T_ + i];
    const float gx1 = sgt[bg_ * 5], gy1 = sgt[bg_ * 5 + 1];
    const float gx2 = sgt[bg_ * 5 + 2], gy2 = sgt[bg_ * 5 + 3];
    const float ew = ax2 - ax1 + 1.0f, eh = ay2 - ay1 + 1.0f;
    const float ecx = ax1 + 0.5f * ew, ecy = ay1 + 0.5f * eh;
    const float gw = gx2 - gx1 + 1.0f, gh = gy2 - gy1 + 1.0f;
    const float gcx = gx1 + 0.5f * gw, gcy = gy1 + 0.5f * gh;
    tg0 = (gcx - ecx) / ew;
    tg1 = (gcy - ecy) / eh;
    tg2 = logf(gw / ew);
    tg3 = logf(gh / eh);
  }
  const float inw = (lab == 1) ? 1.0f : 0.0f;
  const float oww = (lab == 1 || lab == 0) ? uw : 0.0f;

  out[(size_t)b * T_ + i] = (float)lab;  // labels_o [b][a][h][w]
  const size_t ch = ((size_t)b * 36 + (size_t)a * 4) * HW_ + cell;
  float* o1 = out + OUT0_;
  o1[ch] = tg0; o1[ch + HW_] = tg1; o1[ch + 2 * HW_] = tg2; o1[ch + 3 * HW_] = tg3;
  float* o2 = o1 + OUTC_;
  o2[ch] = inw; o2[ch + HW_] = inw; o2[ch + 2 * HW_] = inw; o2[ch + 3 * HW_] = inw;
  float* o3 = o2 + OUTC_;
  o3[ch] = oww; o3[ch + HW_] = oww; o3[ch + 2 * HW_] = oww; o3[ch + 3 * HW_] = oww;
}

extern "C" void kernel_launch(void* const* d_in, const int* in_sizes, int n_in,
                              void* d_out, int out_size, void* d_ws, size_t ws_size,
                              hipStream_t stream) {
  (void)in_sizes; (void)n_in; (void)out_size; (void)ws_size;
  const float* gt = (const float*)d_in[1];   // (32,20,5)
  const float* im = (const float*)d_in[2];   // (32,3)
  float* out = (float*)d_out;

  uint8_t* ws = (uint8_t*)d_ws;
  uint32_t* gmax   = (uint32_t*)(ws + 0);          // 32*32 u32       (4096 B)
  uint32_t* cnt    = (uint32_t*)(ws + 4096);       // 32*2 u32        (256 B)
  uint32_t* sel    = (uint32_t*)(ws + 4352);       // 32*4 u32        (512 B)
  int8_t*   labels = (int8_t*)  (ws + 5120);       // 32*57600 i8     (1.84 MB)
  int8_t*   argmax = (int8_t*)  (ws + 1848320);    // 32*57600 i8     (1.84 MB)
  uint32_t* cand   = (uint32_t*)(ws + 3691520);    // 2*32*57600 u32  (14.7 MB)

  (void)hipMemsetAsync(ws, 0, 4864, stream);  // gmax + cnt + sel

  dim3 blk(256);
  dim3 grd(T_ / 256, B_);  // 225 x 32
  k1_gtmax<<<grd, blk, 0, stream>>>(gt, im, gmax);
  k2_label<<<grd, blk, 0, stream>>>(gt, im, gmax, labels, argmax, cnt, cand);
  k3_select<<<dim3(B_ * 2), dim3(1024), 0, stream>>>(labels, cnt, cand, sel);
  k4_final<<<grd, blk, 0, stream>>>(gt, im, labels, argmax, cnt, sel, out);
}

// Round 3
// 216.077 us; speedup vs baseline: 2.0239x; 1.7065x over previous
//
#include <hip/hip_runtime.h>
#include <stdint.h>

// JAX >= 0.5 defaults jax_threefry_partitionable=True (verified R1: absmax 0.0).
#define JAX_PARTITIONABLE 1

static constexpr int B_   = 32;
static constexpr int NGT_ = 20;
static constexpr int H_   = 64;
static constexpr int W_   = 100;
static constexpr int A_   = 9;
static constexpr int HW_  = H_ * W_;        // 6400
static constexpr int T_   = HW_ * A_;       // 57600
static constexpr int NBLK_ = T_ / 256;      // 225 blocks per (b)
static constexpr uint32_t NUMFG_ = 128u;
static constexpr uint32_t RPNBATCH_ = 256u;
static constexpr int OUT0_ = B_ * T_;
static constexpr int OUTC_ = B_ * 4 * A_ * HW_;

// ---------------- Threefry-2x32-20 (bit-exact vs JAX) ----------------
struct TF2 { uint32_t a, b; };

__host__ __device__ constexpr uint32_t rotl32(uint32_t v, int r) {
  return (v << r) | (v >> (32 - r));
}

__host__ __device__ constexpr TF2 tf2x32(uint32_t k0, uint32_t k1,
                                         uint32_t x0, uint32_t x1) {
  uint32_t ks2 = k0 ^ k1 ^ 0x1BD11BDAu;
  x0 += k0; x1 += k1;
#define TFR_(r) x0 += x1; x1 = rotl32(x1, (r)); x1 ^= x0;
  TFR_(13) TFR_(15) TFR_(26) TFR_(6)
  x0 += k1;  x1 += ks2 + 1u;
  TFR_(17) TFR_(29) TFR_(16) TFR_(24)
  x0 += ks2; x1 += k0 + 2u;
  TFR_(13) TFR_(15) TFR_(26) TFR_(6)
  x0 += k0;  x1 += k1 + 3u;
  TFR_(17) TFR_(29) TFR_(16) TFR_(24)
  x0 += k1;  x1 += ks2 + 4u;
  TFR_(13) TFR_(15) TFR_(26) TFR_(6)
  x0 += ks2; x1 += k0 + 5u;
#undef TFR_
  return TF2{x0, x1};
}

#if JAX_PARTITIONABLE
static constexpr TF2 KFk = tf2x32(0u, 42u, 0u, 0u);
static constexpr TF2 KBk = tf2x32(0u, 42u, 0u, 1u);
static constexpr uint32_t KF0 = KFk.a, KF1 = KFk.b;
static constexpr uint32_t KB0 = KBk.a, KB1 = KBk.b;
#else
static constexpr TF2 R02 = tf2x32(0u, 42u, 0u, 2u);
static constexpr TF2 R13 = tf2x32(0u, 42u, 1u, 3u);
static constexpr uint32_t KF0 = R02.a, KF1 = R13.a;
static constexpr uint32_t KB0 = R02.b, KB1 = R13.b;
#endif

__device__ inline uint32_t mant23(uint32_t k0, uint32_t k1, uint32_t j) {
#if JAX_PARTITIONABLE
  TF2 r = tf2x32(k0, k1, 0u, j);
  return (r.a ^ r.b) >> 9;
#else
  constexpr uint32_t HALF_ = (uint32_t)((uint64_t)B_ * T_ / 2);
  uint32_t lo = (j < HALF_) ? j : j - HALF_;
  TF2 r = tf2x32(k0, k1, lo, lo + HALF_);
  return ((j < HALF_) ? r.a : r.b) >> 9;
#endif
}

// monotone float->uint key; fkey(+0) = 0x80000000
__device__ inline uint32_t fkey(float f) {
  uint32_t u = __float_as_uint(f);
  return (u & 0x80000000u) ? ~u : (u | 0x80000000u);
}

__constant__ float c_anc[9][4] = {
  { -84.f,  -40.f,  99.f,  55.f},
  {-176.f,  -88.f, 191.f, 103.f},
  {-360.f, -184.f, 375.f, 199.f},
  { -56.f,  -56.f,  71.f,  71.f},
  {-120.f, -120.f, 135.f, 135.f},
  {-248.f, -248.f, 263.f, 263.f},
  { -36.f,  -80.f,  51.f,  95.f},
  { -80.f, -168.f,  95.f, 183.f},
  {-168.f, -344.f, 183.f, 359.f},
};

__device__ inline float ov_inside(float ax1, float ay1, float ax2, float ay2,
                                  float aarea,
                                  float gx1, float gy1, float gx2, float gy2) {
#pragma clang fp contract(off)
  float gw = gx2 - gx1 + 1.0f;
  float gh = gy2 - gy1 + 1.0f;
  float garea = gw * gh;
  float iw = fminf(ax2, gx2) - fmaxf(ax1, gx1) + 1.0f;
  float ih = fminf(ay2, gy2) - fmaxf(ay1, gy1) + 1.0f;
  float inter = fmaxf(iw, 0.0f) * fmaxf(ih, 0.0f);
  float ua = aarea + garea - inter;
  return inter / ua;
}

__device__ inline void anchor_of_ac(int a, int cell,
                                    float& ax1, float& ay1, float& ax2, float& ay2) {
#pragma clang fp contract(off)
  const int wx = cell % W_, hy = cell / W_;
  ax1 = c_anc[a][0] + wx * 16.0f;
  ay1 = c_anc[a][1] + hy * 16.0f;
  ax2 = c_anc[a][2] + wx * 16.0f;
  ay2 = c_anc[a][3] + hy * 16.0f;
}

// ---------------- K1: per-(b,g) max IOU key over inside anchors ----------
__global__ __launch_bounds__(256) void k1_gtmax(const float* __restrict__ gt,
                                                const float* __restrict__ im,
                                                uint32_t* __restrict__ gmax) {
#pragma clang fp contract(off)
  const int b = blockIdx.y;
  const int tid = threadIdx.x;
  const int i = blockIdx.x * 256 + tid;
  __shared__ float sgt[NGT_ * 5];
  __shared__ uint32_t skey[NGT_];
  if (tid < NGT_ * 5) sgt[tid] = gt[b * NGT_ * 5 + tid];
  if (tid < NGT_) skey[tid] = 0u;
  __syncthreads();

  const int a = i / HW_, cell = i % HW_;
  float ax1, ay1, ax2, ay2;
  anchor_of_ac(a, cell, ax1, ay1, ax2, ay2);
  const float imh = im[0], imw = im[1];
  const bool inside = (ax1 >= 0.0f) && (ay1 >= 0.0f) && (ax2 < imw) && (ay2 < imh);
  const float aarea = (ax2 - ax1 + 1.0f) * (ay2 - ay1 + 1.0f);

  if (__ballot(inside) != 0ull) {
    for (int g = 0; g < NGT_; ++g) {
      const float gx1 = sgt[g * 5], gy1 = sgt[g * 5 + 1];
      const float gx2 = sgt[g * 5 + 2], gy2 = sgt[g * 5 + 3];
      if (gx2 - gx1 + 1.0f == 1.0f && gy2 - gy1 + 1.0f == 1.0f) continue;
      float ov = ov_inside(ax1, ay1, ax2, ay2, aarea, gx1, gy1, gx2, gy2);
      uint32_t k = inside ? fkey(ov) : 0u;
      for (int d = 1; d < 64; d <<= 1) {
        uint32_t o = (uint32_t)__shfl_xor((int)k, d, 64);
        k = (o > k) ? o : k;
      }
      if ((tid & 63) == 0) atomicMax(&skey[g], k);
    }
  }
  __syncthreads();
  if (tid < NGT_) atomicMax(&gmax[b * 32 + tid], skey[tid]);  // no return use
}

// ---------------- K2: labels + argmax + per-block compacted candidates ----
__global__ __launch_bounds__(256) void k2_label(const float* __restrict__ gt,
                                                const float* __restrict__ im,
                                                const uint32_t* __restrict__ gmax,
                                                int8_t* __restrict__ labels,
                                                int8_t* __restrict__ argmax8,
                                                uint32_t* __restrict__ cntblk,
                                                uint32_t* __restrict__ cand) {
#pragma clang fp contract(off)
  const int b = blockIdx.y;
  const int bx = blockIdx.x;
  const int tid = threadIdx.x;
  const int i = bx * 256 + tid;
  __shared__ float sgt[NGT_ * 5];
  __shared__ uint32_t skey[NGT_];
  __shared__ uint32_t sfgc[4], sbgc[4];
  if (tid < NGT_ * 5) sgt[tid] = gt[b * NGT_ * 5 + tid];
  if (tid < NGT_) skey[tid] = gmax[b * 32 + tid];
  __syncthreads();

  const int a = i / HW_, cell = i % HW_;
  const int t = cell * A_ + a;  // original anchor index (threefry j)
  float ax1, ay1, ax2, ay2;
  anchor_of_ac(a, cell, ax1, ay1, ax2, ay2);
  const float imh = im[0], imw = im[1];
  const bool inside = (ax1 >= 0.0f) && (ay1 >= 0.0f) && (ax2 < imw) && (ay2 < imh);
  const float aarea = (ax2 - ax1 + 1.0f) * (ay2 - ay1 + 1.0f);

  float maxov = -2.0f;
  bool haskeep = false;
  int bg_ = 0;
  if (__ballot(inside) != 0ull) {
    float best = -1e30f;
    for (int g = 0; g < NGT_; ++g) {
      const float gx1 = sgt[g * 5], gy1 = sgt[g * 5 + 1];
      const float gx2 = sgt[g * 5 + 2], gy2 = sgt[g * 5 + 3];
      if (gx2 - gx1 + 1.0f == 1.0f && gy2 - gy1 + 1.0f == 1.0f) continue;
      float ov = ov_inside(ax1, ay1, ax2, ay2, aarea, gx1, gy1, gx2, gy2);
      uint32_t gk = skey[g];
      if (inside && fkey(ov) == gk && gk != 0x80000000u) haskeep = true;
      if (ov > best) { best = ov; bg_ = g; }  // first-max == jnp.argmax
    }
    if (inside) maxov = fmaxf(best, 0.0f);
    else bg_ = 0;
  }
  int lab = -1;
  if (inside) {
    if (maxov < 0.3f) lab = 0;
    if (haskeep) lab = 1;
    if (maxov >= 0.7f) lab = 1;
  }
  labels[(size_t)b * T_ + i] = (int8_t)lab;
  argmax8[(size_t)b * T_ + i] = (int8_t)bg_;

  uint32_t m = 0;
  if (lab >= 0)
    m = mant23(lab ? KF0 : KB0, lab ? KF1 : KB1, (uint32_t)(b * T_ + t));

  // ---- block-local compaction, zero global atomics ----
  const int wv = tid >> 6, lane = tid & 63;
  const unsigned long long mk1 = __ballot(lab == 1);
  const unsigned long long mk0 = __ballot(lab == 0);
  if (lane == 0) { sfgc[wv] = (uint32_t)__popcll(mk1); sbgc[wv] = (uint32_t)__popcll(mk0); }
  __syncthreads();
  uint32_t fgbase = 0, bgbase = 0, fgtot = 0, bgtot = 0;
  for (int w2 = 0; w2 < 4; ++w2) {
    if (w2 < wv) { fgbase += sfgc[w2]; bgbase += sbgc[w2]; }
    fgtot += sfgc[w2]; bgtot += sbgc[w2];
  }
  const unsigned long long lmask = (1ull << lane) - 1ull;
  if (lab == 1) {
    uint32_t off = fgbase + (uint32_t)__popcll(mk1 & lmask);
    cand[((size_t)0 * B_ + b) * T_ + (size_t)bx * 256 + off] = m;
  } else if (lab == 0) {
    uint32_t off = bgbase + (uint32_t)__popcll(mk0 & lmask);
    cand[((size_t)1 * B_ + b) * T_ + (size_t)bx * 256 + off] = m;
  }
  if (tid == 0) {
    cntblk[(0 * B_ + b) * NBLK_ + bx] = fgtot;
    cntblk[(1 * B_ + b) * NBLK_ + bx] = bgtot;
  }
}

// ---------------- K3: K-th smallest over segmented candidates ------------
__device__ inline void find_kth1024(uint32_t* hist, int n, uint32_t target, int tid,
                                    uint32_t* wsum, uint32_t* res) {
  const int C = n >> 10;
  const int base = tid * C;
  uint32_t s = 0;
  for (int i = 0; i < C; ++i) s += hist[base + i];
  uint32_t v = s;
  for (int d = 1; d < 64; d <<= 1) {
    uint32_t u = (uint32_t)__shfl_up((int)v, d, 64);
    if ((tid & 63) >= d) v += u;
  }
  const int wv = tid >> 6;
  if ((tid & 63) == 63) wsum[wv] = v;
  __syncthreads();
  uint32_t woff = 0;
  for (int w2 = 0; w2 < wv; ++w2) woff += wsum[w2];
  uint32_t c = woff + v - s;
  for (int i = 0; i < C; ++i) {
    uint32_t h = hist[base + i];
    if (h != 0u && target >= c && target < c + h) {
      res[0] = (uint32_t)(base + i);
      res[1] = c;
    }
    c += h;
  }
  __syncthreads();
}

__global__ __launch_bounds__(1024) void k3_select(const int8_t* __restrict__ labels,
                                                  const uint32_t* __restrict__ cntblk,
                                                  const uint32_t* __restrict__ cand,
                                                  uint32_t* __restrict__ cnt,
                                                  uint32_t* __restrict__ sel) {
  const int b = blockIdx.x >> 1;
  const int cls = blockIdx.x & 1;  // 0=fg, 1=bg
  const int tid = threadIdx.x;
  __shared__ uint32_t scnt[NBLK_];
  __shared__ uint32_t hist[4096];
  __shared__ uint32_t wsum[16];
  __shared__ uint32_t res[2];
  __shared__ uint32_t lcnt, sTot, sCf;

  if (tid == 0) { sTot = 0u; sCf = 0u; }
  __syncthreads();
  if (tid < NBLK_) {
    uint32_t c = cntblk[(cls * B_ + b) * NBLK_ + tid];
    scnt[tid] = c;
    atomicAdd(&sTot, c);
    if (cls == 1) atomicAdd(&sCf, cntblk[(0 * B_ + b) * NBLK_ + tid]);
  }
  __syncthreads();
  const uint32_t n = sTot;
  const uint32_t cf = (cls == 0) ? n : sCf;
  if (tid == 0) cnt[b * 2 + cls] = n;  // k4 reads this (plain store, pre-k4 launch)
  const uint32_t fgk = cf < NUMFG_ ? cf : NUMFG_;
  const uint32_t K = (cls == 0) ? NUMFG_ : RPNBATCH_ - fgk;
  if (n <= K) {
    if (tid == 0) { sel[b * 4 + cls * 2] = 0xFFFFFFFFu; sel[b * 4 + cls * 2 + 1] = 0xFFFFFFFFu; }
    return;
  }
  const uint32_t* list = cand + ((size_t)cls * B_ + b) * T_;

  // level 1: top 11 bits
  for (int i = tid; i < 2048; i += 1024) hist[i] = 0u;
  __syncthreads();
  for (int gi = tid; gi < T_; gi += 1024)
    if ((uint32_t)(gi & 255) < scnt[gi >> 8]) atomicAdd(&hist[list[gi] >> 12], 1u);
  __syncthreads();
  find_kth1024(hist, 2048, K - 1u, tid, wsum, res);
  const uint32_t b1 = res[0], cb1 = res[1];
  __syncthreads();

  // level 2: low 12 bits within bucket b1
  for (int i = tid; i < 4096; i += 1024) hist[i] = 0u;
  __syncthreads();
  for (int gi = tid; gi < T_; gi += 1024)
    if ((uint32_t)(gi & 255) < scnt[gi >> 8]) {
      uint32_t m = list[gi];
      if ((m >> 12) == b1) atomicAdd(&hist[m & 0xFFFu], 1u);
    }
  __syncthreads();
  find_kth1024(hist, 4096, K - 1u - cb1, tid, wsum, res);
  const uint32_t b2 = res[0], cb2 = res[1];
  const uint32_t Mstar = (b1 << 12) | b2;
  const uint32_t need = K - cb1 - cb2;
  const uint32_t cnteq = hist[b2];
  __syncthreads();

  uint32_t tstar = 0xFFFFFFFFu;
  if (need < cnteq) {  // mantissa tie straddles boundary: break on anchor index
    const int8_t want = (cls == 0) ? (int8_t)1 : (int8_t)0;
    const uint32_t k0 = (cls == 0) ? KF0 : KB0;
    const uint32_t k1 = (cls == 0) ? KF1 : KB1;
    const int8_t* lrow = labels + (size_t)b * T_;
    if (tid == 0) lcnt = 0u;
    __syncthreads();
    for (int s = tid; s < T_; s += 1024) {
      if (lrow[s] == want) {
        int aa = s / HW_, cc = s % HW_;
        uint32_t t = (uint32_t)(cc * A_ + aa);
        if (mant23(k0, k1, (uint32_t)b * (uint32_t)T_ + t) == Mstar) {
          uint32_t p = atomicAdd(&lcnt, 1u);
          if (p < 4096u) hist[p] = t;
        }
      }
    }
    __syncthreads();
    if (tid == 0) {
      uint32_t nn = lcnt < 4096u ? lcnt : 4096u;
      uint32_t prev = 0u;
      for (uint32_t kk = 0; kk < need; ++kk) {
        uint32_t mn = 0xFFFFFFFFu;
        for (uint32_t i2 = 0; i2 < nn; ++i2) {
          uint32_t vv = hist[i2];
          if ((kk == 0u || vv > prev) && vv < mn) mn = vv;
        }
        prev = mn;
      }
      tstar = prev;
    }
  }
  if (tid == 0) { sel[b * 4 + cls * 2] = Mstar; sel[b * 4 + cls * 2 + 1] = tstar; }
}

// ---------------- K4: finalize + write all outputs -----------------------
__global__ __launch_bounds__(256) void k4_final(const float* __restrict__ gt,
                                                const float* __restrict__ im,
                                                const int8_t* __restrict__ labels,
                                                const int8_t* __restrict__ argmax8,
                                                const uint32_t* __restrict__ cnt,
                                                const uint32_t* __restrict__ sel,
                                                float* __restrict__ out) {
#pragma clang fp contract(off)
  const int b = blockIdx.y;
  const int tid = threadIdx.x;
  const int i = blockIdx.x * 256 + tid;
  __shared__ float sgt[NGT_ * 5];
  if (tid < NGT_ * 5) sgt[tid] = gt[b * NGT_ * 5 + tid];
  __syncthreads();

  const int a = i / HW_, cell = i % HW_;
  const int t = cell * A_ + a;
  float ax1, ay1, ax2, ay2;
  anchor_of_ac(a, cell, ax1, ay1, ax2, ay2);
  const float imh = im[0], imw = im[1];
  const bool inside = (ax1 >= 0.0f) && (ay1 >= 0.0f) && (ax2 < imw) && (ay2 < imh);

  int lab = labels[(size_t)b * T_ + i];
  const uint32_t j = (uint32_t)(b * T_ + t);
  if (lab == 1) {
    uint32_t m = mant23(KF0, KF1, j);
    uint32_t Ms = sel[b * 4 + 0], ts = sel[b * 4 + 1];
    if (!(m < Ms || (m == Ms && (uint32_t)t <= ts))) lab = -1;
  } else if (lab == 0) {
    uint32_t m = mant23(KB0, KB1, j);
    uint32_t Ms = sel[b * 4 + 2], ts = sel[b * 4 + 3];
    if (!(m < Ms || (m == Ms && (uint32_t)t <= ts))) lab = -1;
  }

  const uint32_t cf = cnt[b * 2 + 0];
  const uint32_t cbn = cnt[b * 2 + 1];
  const uint32_t fgk = cf < NUMFG_ ? cf : NUMFG_;
  const uint32_t nbg = RPNBATCH_ - fgk;
  const uint32_t bgk = cbn < nbg ? cbn : nbg;
  const float uw = 1.0f / (float)(fgk + bgk);

  float tg0 = 0.f, tg1 = 0.f, tg2 = 0.f, tg3 = 0.f;
  if (inside) {
    const int bg_ = argmax8[(size_t)b * T_ + i];
    const float gx1 = sgt[bg_ * 5], gy1 = sgt[bg_ * 5 + 1];
    const float gx2 = sgt[bg_ * 5 + 2], gy2 = sgt[bg_ * 5 + 3];
    const float ew = ax2 - ax1 + 1.0f, eh = ay2 - ay1 + 1.0f;
    const float ecx = ax1 + 0.5f * ew, ecy = ay1 + 0.5f * eh;
    const float gw = gx2 - gx1 + 1.0f, gh = gy2 - gy1 + 1.0f;
    const float gcx = gx1 + 0.5f * gw, gcy = gy1 + 0.5f * gh;
    tg0 = (gcx - ecx) / ew;
    tg1 = (gcy - ecy) / eh;
    tg2 = logf(gw / ew);
    tg3 = logf(gh / eh);
  }
  const float inw = (lab == 1) ? 1.0f : 0.0f;
  const float oww = (lab == 1 || lab == 0) ? uw : 0.0f;

  out[(size_t)b * T_ + i] = (float)lab;
  const size_t ch = ((size_t)b * 36 + (size_t)a * 4) * HW_ + cell;
  float* o1 = out + OUT0_;
  o1[ch] = tg0; o1[ch + HW_] = tg1; o1[ch + 2 * HW_] = tg2; o1[ch + 3 * HW_] = tg3;
  float* o2 = o1 + OUTC_;
  o2[ch] = inw; o2[ch + HW_] = inw; o2[ch + 2 * HW_] = inw; o2[ch + 3 * HW_] = inw;
  float* o3 = o2 + OUTC_;
  o3[ch] = oww; o3[ch + HW_] = oww; o3[ch + 2 * HW_] = oww; o3[ch + 3 * HW_] = oww;
}

extern "C" void kernel_launch(void* const* d_in, const int* in_sizes, int n_in,
                              void* d_out, int out_size, void* d_ws, size_t ws_size,
                              hipStream_t stream) {
  (void)in_sizes; (void)n_in; (void)out_size; (void)ws_size;
  const float* gt = (const float*)d_in[1];   // (32,20,5)
  const float* im = (const float*)d_in[2];   // (32,3)
  float* out = (float*)d_out;

  uint8_t* ws = (uint8_t*)d_ws;
  uint32_t* gmax   = (uint32_t*)(ws + 0);          // 32*32 u32        (4096 B)
  uint32_t* cnt    = (uint32_t*)(ws + 4096);       // 32*2 u32         (256 B)
  uint32_t* sel    = (uint32_t*)(ws + 4352);       // 32*4 u32         (512 B)
  uint32_t* cntblk = (uint32_t*)(ws + 4864);       // 2*32*225 u32     (57.6 KB)
  int8_t*   labels = (int8_t*)  (ws + 62464);      // 32*57600 i8      (1.84 MB)
  int8_t*   argmax = (int8_t*)  (ws + 1905664);    // 32*57600 i8      (1.84 MB)
  uint32_t* cand   = (uint32_t*)(ws + 3748864);    // 2*32*57600 u32   (14.7 MB)

  (void)hipMemsetAsync(ws, 0, 4096, stream);  // gmax only (rest fully written)

  dim3 blk(256);
  dim3 grd(NBLK_, B_);  // 225 x 32
  k1_gtmax<<<grd, blk, 0, stream>>>(gt, im, gmax);
  k2_label<<<grd, blk, 0, stream>>>(gt, im, gmax, labels, argmax, cntblk, cand);
  k3_select<<<dim3(B_ * 2), dim3(1024), 0, stream>>>(labels, cntblk, cand, cnt, sel);
  k4_final<<<grd, blk, 0, stream>>>(gt, im, labels, argmax, cnt, sel, out);
}

// Round 4
// 208.777 us; speedup vs baseline: 2.0947x; 1.0350x over previous
//
#include <hip/hip_runtime.h>
#include <stdint.h>

// JAX >= 0.5 defaults jax_threefry_partitionable=True (verified R1: absmax 0.0).
#define JAX_PARTITIONABLE 1

static constexpr int B_   = 32;
static constexpr int NGT_ = 20;
static constexpr int H_   = 64;
static constexpr int W_   = 100;
static constexpr int A_   = 9;
static constexpr int HW_  = H_ * W_;        // 6400
static constexpr int T_   = HW_ * A_;       // 57600
static constexpr int NBLK_ = T_ / 256;      // 225
static constexpr uint32_t NUMFG_ = 128u;
static constexpr uint32_t RPNBATCH_ = 256u;
static constexpr int OUT0_ = B_ * T_;
static constexpr int OUTC_ = B_ * 4 * A_ * HW_;

// ---------------- Threefry-2x32-20 (bit-exact vs JAX) ----------------
struct TF2 { uint32_t a, b; };

__host__ __device__ constexpr uint32_t rotl32(uint32_t v, int r) {
  return (v << r) | (v >> (32 - r));
}

__host__ __device__ constexpr TF2 tf2x32(uint32_t k0, uint32_t k1,
                                         uint32_t x0, uint32_t x1) {
  uint32_t ks2 = k0 ^ k1 ^ 0x1BD11BDAu;
  x0 += k0; x1 += k1;
#define TFR_(r) x0 += x1; x1 = rotl32(x1, (r)); x1 ^= x0;
  TFR_(13) TFR_(15) TFR_(26) TFR_(6)
  x0 += k1;  x1 += ks2 + 1u;
  TFR_(17) TFR_(29) TFR_(16) TFR_(24)
  x0 += ks2; x1 += k0 + 2u;
  TFR_(13) TFR_(15) TFR_(26) TFR_(6)
  x0 += k0;  x1 += k1 + 3u;
  TFR_(17) TFR_(29) TFR_(16) TFR_(24)
  x0 += k1;  x1 += ks2 + 4u;
  TFR_(13) TFR_(15) TFR_(26) TFR_(6)
  x0 += ks2; x1 += k0 + 5u;
#undef TFR_
  return TF2{x0, x1};
}

#if JAX_PARTITIONABLE
static constexpr TF2 KFk = tf2x32(0u, 42u, 0u, 0u);
static constexpr TF2 KBk = tf2x32(0u, 42u, 0u, 1u);
static constexpr uint32_t KF0 = KFk.a, KF1 = KFk.b;
static constexpr uint32_t KB0 = KBk.a, KB1 = KBk.b;
#else
static constexpr TF2 R02 = tf2x32(0u, 42u, 0u, 2u);
static constexpr TF2 R13 = tf2x32(0u, 42u, 1u, 3u);
static constexpr uint32_t KF0 = R02.a, KF1 = R13.a;
static constexpr uint32_t KB0 = R02.b, KB1 = R13.b;
#endif

__device__ inline uint32_t mant23(uint32_t k0, uint32_t k1, uint32_t j) {
#if JAX_PARTITIONABLE
  TF2 r = tf2x32(k0, k1, 0u, j);
  return (r.a ^ r.b) >> 9;
#else
  constexpr uint32_t HALF_ = (uint32_t)((uint64_t)B_ * T_ / 2);
  uint32_t lo = (j < HALF_) ? j : j - HALF_;
  TF2 r = tf2x32(k0, k1, lo, lo + HALF_);
  return ((j < HALF_) ? r.a : r.b) >> 9;
#endif
}

// monotone float->uint key; fkey(+0) = 0x80000000; strictly monotone, equality-preserving
__device__ inline uint32_t fkey(float f) {
  uint32_t u = __float_as_uint(f);
  return (u & 0x80000000u) ? ~u : (u | 0x80000000u);
}

__constant__ float c_anc[9][4] = {
  { -84.f,  -40.f,  99.f,  55.f},
  {-176.f,  -88.f, 191.f, 103.f},
  {-360.f, -184.f, 375.f, 199.f},
  { -56.f,  -56.f,  71.f,  71.f},
  {-120.f, -120.f, 135.f, 135.f},
  {-248.f, -248.f, 263.f, 263.f},
  { -36.f,  -80.f,  51.f,  95.f},
  { -80.f, -168.f,  95.f, 183.f},
  {-168.f, -344.f, 183.f, 359.f},
};

// ---------------- K1: the ONE full IOU pass --------------------------------
// 4 consecutive cells per thread, same anchor-type a. Outputs per-anchor
// bestkey (fkey of max ov over valid gts) + argmax byte, and per-(b,g) gmax.
__global__ __launch_bounds__(192) void k1_iou(const float* __restrict__ gt,
                                              const float* __restrict__ im,
                                              uint32_t* __restrict__ gmax,
                                              uint32_t* __restrict__ bkey,
                                              uint32_t* __restrict__ barg) {
#pragma clang fp contract(off)
  const int b = blockIdx.y;
  const int tid = threadIdx.x;
  const int iq = blockIdx.x * 192 + tid;     // [0, 14400) exactly (75*192)
  __shared__ float4 sbox[NGT_];
  __shared__ float sgar[NGT_];
  __shared__ uint32_t skey[NGT_];
  __shared__ uint32_t smask;

  bool valid = false;
  if (tid < NGT_) {
    const float x1 = gt[(b * NGT_ + tid) * 5 + 0];
    const float y1 = gt[(b * NGT_ + tid) * 5 + 1];
    const float x2 = gt[(b * NGT_ + tid) * 5 + 2];
    const float y2 = gt[(b * NGT_ + tid) * 5 + 3];
    const float gw = x2 - x1 + 1.0f, gh = y2 - y1 + 1.0f;
    valid = !(gw == 1.0f && gh == 1.0f);
    sbox[tid] = make_float4(x1, y1, x2, y2);
    sgar[tid] = gw * gh;
    skey[tid] = 0u;
  }
  unsigned long long mv = __ballot(valid);   // wave 0 holds lanes 0..19
  if (tid == 0) smask = (uint32_t)mv;
  __syncthreads();

  const int aa = iq / 1600;                  // wave-uniform (1600 % 64 == 0)
  const int cell0 = (iq % 1600) * 4;
  const float imh = im[0], imw = im[1];
  const float bx1 = c_anc[aa][0], by1 = c_anc[aa][1];
  const float bx2 = c_anc[aa][2], by2 = c_anc[aa][3];

  float ax1[4], ay1[4], ax2[4], ay2[4], aarea[4];
  bool ins[4];
#pragma unroll
  for (int c = 0; c < 4; ++c) {
    const int cell = cell0 + c;
    const int wx = cell % W_, hy = cell / W_;
    ax1[c] = bx1 + wx * 16.0f;
    ay1[c] = by1 + hy * 16.0f;
    ax2[c] = bx2 + wx * 16.0f;
    ay2[c] = by2 + hy * 16.0f;
    ins[c] = (ax1[c] >= 0.0f) && (ay1[c] >= 0.0f) && (ax2[c] < imw) && (ay2[c] < imh);
    aarea[c] = (ax2[c] - ax1[c] + 1.0f) * (ay2[c] - ay1[c] + 1.0f);
  }

  uint32_t bk[4] = {0u, 0u, 0u, 0u};
  uint32_t ba[4] = {0u, 0u, 0u, 0u};
  const uint32_t mask = smask;
  const bool anyin = __ballot(ins[0] || ins[1] || ins[2] || ins[3]) != 0ull;

  if (anyin) {
    for (int g = 0; g < NGT_; ++g) {
      if (!((mask >> g) & 1u)) continue;
      const float4 gb = sbox[g];         // one ds_read_b128, broadcast
      const float gar = sgar[g];
      uint32_t gm = 0u;
#pragma unroll
      for (int c = 0; c < 4; ++c) {
        float iw = fminf(ax2[c], gb.z) - fmaxf(ax1[c], gb.x) + 1.0f;
        float ih = fminf(ay2[c], gb.w) - fmaxf(ay1[c], gb.y) + 1.0f;
        float inter = fmaxf(iw, 0.0f) * fmaxf(ih, 0.0f);
        float ua = aarea[c] + gar - inter;
        float ov = inter / ua;             // IEEE div, bit-exact vs numpy
        uint32_t k = ins[c] ? fkey(ov) : 0u;
        if (k > bk[c]) { bk[c] = k; ba[c] = (uint32_t)g; }  // first-max
        gm = k > gm ? k : gm;
      }
      // butterfly max, amortized over 4 cells
      for (int d = 1; d < 64; d <<= 1) {
        uint32_t o = (uint32_t)__shfl_xor((int)gm, d, 64);
        gm = (o > gm) ? o : gm;
      }
      if ((tid & 63) == 0) atomicMax(&skey[g], gm);
    }
  }
  __syncthreads();
  if (tid < NGT_) atomicMax(&gmax[b * 32 + tid], skey[tid]);  // fire-and-forget

  const size_t base = (size_t)b * T_ + (size_t)aa * HW_ + cell0;  // 16B aligned
  *(uint4*)(bkey + base) = make_uint4(bk[0], bk[1], bk[2], bk[3]);
  barg[base >> 2] = ba[0] | (ba[1] << 8) | (ba[2] << 16) | (ba[3] << 24);
}

// ---------------- K2: labels from cached keys + filtered haskeep recheck ---
__global__ __launch_bounds__(256) void k2_label(const float* __restrict__ gt,
                                                const float* __restrict__ im,
                                                const uint32_t* __restrict__ gmax,
                                                const uint32_t* __restrict__ bkey,
                                                int8_t* __restrict__ labels,
                                                uint32_t* __restrict__ cntblk,
                                                uint32_t* __restrict__ cand) {
#pragma clang fp contract(off)
  const int b = blockIdx.y;
  const int bx = blockIdx.x;
  const int tid = threadIdx.x;
  const int i = bx * 256 + tid;
  __shared__ float4 sbox[NGT_];
  __shared__ float sgar[NGT_];
  __shared__ uint32_t skey[NGT_];
  __shared__ uint32_t smask, sminG;
  __shared__ uint32_t sfgc[4], sbgc[4];

  bool valid = false;
  uint32_t myk = 0xFFFFFFFFu;
  if (tid < NGT_) {
    const float x1 = gt[(b * NGT_ + tid) * 5 + 0];
    const float y1 = gt[(b * NGT_ + tid) * 5 + 1];
    const float x2 = gt[(b * NGT_ + tid) * 5 + 2];
    const float y2 = gt[(b * NGT_ + tid) * 5 + 3];
    const float gw = x2 - x1 + 1.0f, gh = y2 - y1 + 1.0f;
    valid = !(gw == 1.0f && gh == 1.0f);
    sbox[tid] = make_float4(x1, y1, x2, y2);
    sgar[tid] = gw * gh;
    const uint32_t gk = gmax[b * 32 + tid];
    skey[tid] = gk;
    if (valid && gk > 0x80000000u) myk = gk;   // exclude fkey(0) sentinel
  }
  unsigned long long mv = __ballot(valid);
  // wave-0 butterfly min for min valid gmax
  uint32_t mn = myk;
  for (int d = 1; d < 64; d <<= 1) {
    uint32_t o = (uint32_t)__shfl_xor((int)mn, d, 64);
    mn = (o < mn) ? o : mn;
  }
  if (tid == 0) { smask = (uint32_t)mv; sminG = mn; }
  __syncthreads();

  const int a = i / HW_, cell = i % HW_;
  const int t = cell * A_ + a;               // original anchor index (threefry j)
  const float imh = im[0], imw = im[1];
  const float ax1 = c_anc[a][0] + (cell % W_) * 16.0f;
  const float ay1 = c_anc[a][1] + (cell / W_) * 16.0f;
  const float ax2 = c_anc[a][2] + (cell % W_) * 16.0f;
  const float ay2 = c_anc[a][3] + (cell / W_) * 16.0f;
  const bool inside = (ax1 >= 0.0f) && (ay1 >= 0.0f) && (ax2 < imw) && (ay2 < imh);
  const float aarea = (ax2 - ax1 + 1.0f) * (ay2 - ay1 + 1.0f);

  const uint32_t bk = bkey[(size_t)b * T_ + i];
  const float maxovf = __uint_as_float(bk & 0x7FFFFFFFu);  // inside => ov>=0

  int lab = -1;
  if (inside && maxovf < 0.3f) lab = 0;

  // haskeep possible only if bestkey >= min valid gmax (exact bound);
  // irrelevant if already >= 0.7 (label 1 either way)
  bool haskeep = false;
  const bool needck = inside && bk >= sminG && maxovf < 0.7f;
  if (__ballot(needck) != 0ull) {
    const uint32_t mask = smask;
    for (int g = 0; g < NGT_; ++g) {
      if (!((mask >> g) & 1u)) continue;
      const float4 gb = sbox[g];
      const float gar = sgar[g];
      float iw = fminf(ax2, gb.z) - fmaxf(ax1, gb.x) + 1.0f;
      float ih = fminf(ay2, gb.w) - fmaxf(ay1, gb.y) + 1.0f;
      float inter = fmaxf(iw, 0.0f) * fmaxf(ih, 0.0f);
      float ua = aarea + gar - inter;
      float ov = inter / ua;
      const uint32_t gk = skey[g];
      if (needck && gk > 0x80000000u && fkey(ov) == gk) haskeep = true;
    }
  }
  if (haskeep) lab = 1;
  if (inside && maxovf >= 0.7f) lab = 1;
  labels[(size_t)b * T_ + i] = (int8_t)lab;

  uint32_t m = 0;
  if (lab >= 0)
    m = mant23(lab ? KF0 : KB0, lab ? KF1 : KB1, (uint32_t)(b * T_ + t));

  // block-local compaction, zero global atomics
  const int wv = tid >> 6, lane = tid & 63;
  const unsigned long long mk1 = __ballot(lab == 1);
  const unsigned long long mk0 = __ballot(lab == 0);
  if (lane == 0) { sfgc[wv] = (uint32_t)__popcll(mk1); sbgc[wv] = (uint32_t)__popcll(mk0); }
  __syncthreads();
  uint32_t fgbase = 0, bgbase = 0, fgtot = 0, bgtot = 0;
  for (int w2 = 0; w2 < 4; ++w2) {
    if (w2 < wv) { fgbase += sfgc[w2]; bgbase += sbgc[w2]; }
    fgtot += sfgc[w2]; bgtot += sbgc[w2];
  }
  const unsigned long long lmask = (1ull << lane) - 1ull;
  if (lab == 1) {
    uint32_t off = fgbase + (uint32_t)__popcll(mk1 & lmask);
    cand[((size_t)0 * B_ + b) * T_ + (size_t)bx * 256 + off] = m;
  } else if (lab == 0) {
    uint32_t off = bgbase + (uint32_t)__popcll(mk0 & lmask);
    cand[((size_t)1 * B_ + b) * T_ + (size_t)bx * 256 + off] = m;
  }
  if (tid == 0) {
    cntblk[(0 * B_ + b) * NBLK_ + bx] = fgtot;
    cntblk[(1 * B_ + b) * NBLK_ + bx] = bgtot;
  }
}

// ---------------- K3: K-th smallest over segmented candidates ------------
__device__ inline void find_kth1024(uint32_t* hist, int n, uint32_t target, int tid,
                                    uint32_t* wsum, uint32_t* res) {
  const int C = n >> 10;
  const int base = tid * C;
  uint32_t s = 0;
  for (int i = 0; i < C; ++i) s += hist[base + i];
  uint32_t v = s;
  for (int d = 1; d < 64; d <<= 1) {
    uint32_t u = (uint32_t)__shfl_up((int)v, d, 64);
    if ((tid & 63) >= d) v += u;
  }
  const int wv = tid >> 6;
  if ((tid & 63) == 63) wsum[wv] = v;
  __syncthreads();
  uint32_t woff = 0;
  for (int w2 = 0; w2 < wv; ++w2) woff += wsum[w2];
  uint32_t c = woff + v - s;
  for (int i = 0; i < C; ++i) {
    uint32_t h = hist[base + i];
    if (h != 0u && target >= c && target < c + h) {
      res[0] = (uint32_t)(base + i);
      res[1] = c;
    }
    c += h;
  }
  __syncthreads();
}

__global__ __launch_bounds__(1024) void k3_select(const int8_t* __restrict__ labels,
                                                  const uint32_t* __restrict__ cntblk,
                                                  const uint32_t* __restrict__ cand,
                                                  uint32_t* __restrict__ cnt,
                                                  uint32_t* __restrict__ sel) {
  const int b = blockIdx.x >> 1;
  const int cls = blockIdx.x & 1;  // 0=fg, 1=bg
  const int tid = threadIdx.x;
  __shared__ uint32_t scnt[NBLK_];
  __shared__ uint32_t hist[4096];
  __shared__ uint32_t wsum[16];
  __shared__ uint32_t res[2];
  __shared__ uint32_t lcnt, sTot, sCf;

  if (tid == 0) { sTot = 0u; sCf = 0u; }
  __syncthreads();
  if (tid < NBLK_) {
    uint32_t c = cntblk[(cls * B_ + b) * NBLK_ + tid];
    scnt[tid] = c;
    atomicAdd(&sTot, c);
    if (cls == 1) atomicAdd(&sCf, cntblk[(0 * B_ + b) * NBLK_ + tid]);
  }
  __syncthreads();
  const uint32_t n = sTot;
  const uint32_t cf = (cls == 0) ? n : sCf;
  if (tid == 0) cnt[b * 2 + cls] = n;
  const uint32_t fgk = cf < NUMFG_ ? cf : NUMFG_;
  const uint32_t K = (cls == 0) ? NUMFG_ : RPNBATCH_ - fgk;
  if (n <= K) {
    if (tid == 0) { sel[b * 4 + cls * 2] = 0xFFFFFFFFu; sel[b * 4 + cls * 2 + 1] = 0xFFFFFFFFu; }
    return;
  }
  const uint32_t* list = cand + ((size_t)cls * B_ + b) * T_;

  for (int i = tid; i < 2048; i += 1024) hist[i] = 0u;
  __syncthreads();
  for (int gi = tid; gi < T_; gi += 1024)
    if ((uint32_t)(gi & 255) < scnt[gi >> 8]) atomicAdd(&hist[list[gi] >> 12], 1u);
  __syncthreads();
  find_kth1024(hist, 2048, K - 1u, tid, wsum, res);
  const uint32_t b1 = res[0], cb1 = res[1];
  __syncthreads();

  for (int i = tid; i < 4096; i += 1024) hist[i] = 0u;
  __syncthreads();
  for (int gi = tid; gi < T_; gi += 1024)
    if ((uint32_t)(gi & 255) < scnt[gi >> 8]) {
      uint32_t m = list[gi];
      if ((m >> 12) == b1) atomicAdd(&hist[m & 0xFFFu], 1u);
    }
  __syncthreads();
  find_kth1024(hist, 4096, K - 1u - cb1, tid, wsum, res);
  const uint32_t b2 = res[0], cb2 = res[1];
  const uint32_t Mstar = (b1 << 12) | b2;
  const uint32_t need = K - cb1 - cb2;
  const uint32_t cnteq = hist[b2];
  __syncthreads();

  uint32_t tstar = 0xFFFFFFFFu;
  if (need < cnteq) {  // mantissa tie straddles boundary: break on anchor index
    const int8_t want = (cls == 0) ? (int8_t)1 : (int8_t)0;
    const uint32_t k0 = (cls == 0) ? KF0 : KB0;
    const uint32_t k1 = (cls == 0) ? KF1 : KB1;
    const int8_t* lrow = labels + (size_t)b * T_;
    if (tid == 0) lcnt = 0u;
    __syncthreads();
    for (int s = tid; s < T_; s += 1024) {
      if (lrow[s] == want) {
        int aa = s / HW_, cc = s % HW_;
        uint32_t t = (uint32_t)(cc * A_ + aa);
        if (mant23(k0, k1, (uint32_t)b * (uint32_t)T_ + t) == Mstar) {
          uint32_t p = atomicAdd(&lcnt, 1u);
          if (p < 4096u) hist[p] = t;
        }
      }
    }
    __syncthreads();
    if (tid == 0) {
      uint32_t nn = lcnt < 4096u ? lcnt : 4096u;
      uint32_t prev = 0u;
      for (uint32_t kk = 0; kk < need; ++kk) {
        uint32_t mn2 = 0xFFFFFFFFu;
        for (uint32_t i2 = 0; i2 < nn; ++i2) {
          uint32_t vv = hist[i2];
          if ((kk == 0u || vv > prev) && vv < mn2) mn2 = vv;
        }
        prev = mn2;
      }
      tstar = prev;
    }
  }
  if (tid == 0) { sel[b * 4 + cls * 2] = Mstar; sel[b * 4 + cls * 2 + 1] = tstar; }
}

// ---------------- K4: finalize + write all outputs -----------------------
__global__ __launch_bounds__(256) void k4_final(const float* __restrict__ gt,
                                                const float* __restrict__ im,
                                                const int8_t* __restrict__ labels,
                                                const int8_t* __restrict__ argmax8,
                                                const uint32_t* __restrict__ cnt,
                                                const uint32_t* __restrict__ sel,
                                                float* __restrict__ out) {
#pragma clang fp contract(off)
  const int b = blockIdx.y;
  const int tid = threadIdx.x;
  const int i = blockIdx.x * 256 + tid;
  __shared__ float sgt[NGT_ * 5];
  if (tid < NGT_ * 5) sgt[tid] = gt[b * NGT_ * 5 + tid];
  __syncthreads();

  const int a = i / HW_, cell = i % HW_;
  const int t = cell * A_ + a;
  const float imh = im[0], imw = im[1];
  const float ax1 = c_anc[a][0] + (cell % W_) * 16.0f;
  const float ay1 = c_anc[a][1] + (cell / W_) * 16.0f;
  const float ax2 = c_anc[a][2] + (cell % W_) * 16.0f;
  const float ay2 = c_anc[a][3] + (cell / W_) * 16.0f;
  const bool inside = (ax1 >= 0.0f) && (ay1 >= 0.0f) && (ax2 < imw) && (ay2 < imh);

  int lab = labels[(size_t)b * T_ + i];
  const uint32_t j = (uint32_t)(b * T_ + t);
  if (lab == 1) {
    uint32_t m = mant23(KF0, KF1, j);
    uint32_t Ms = sel[b * 4 + 0], ts = sel[b * 4 + 1];
    if (!(m < Ms || (m == Ms && (uint32_t)t <= ts))) lab = -1;
  } else if (lab == 0) {
    uint32_t m = mant23(KB0, KB1, j);
    uint32_t Ms = sel[b * 4 + 2], ts = sel[b * 4 + 3];
    if (!(m < Ms || (m == Ms && (uint32_t)t <= ts))) lab = -1;
  }

  const uint32_t cf = cnt[b * 2 + 0];
  const uint32_t cbn = cnt[b * 2 + 1];
  const uint32_t fgk = cf < NUMFG_ ? cf : NUMFG_;
  const uint32_t nbg = RPNBATCH_ - fgk;
  const uint32_t bgk = cbn < nbg ? cbn : nbg;
  const float uw = 1.0f / (float)(fgk + bgk);

  float tg0 = 0.f, tg1 = 0.f, tg2 = 0.f, tg3 = 0.f;
  if (inside) {
    const int bg_ = argmax8[(size_t)b * T_ + i];
    const float gx1 = sgt[bg_ * 5], gy1 = sgt[bg_ * 5 + 1];
    const float gx2 = sgt[bg_ * 5 + 2], gy2 = sgt[bg_ * 5 + 3];
    const float ew = ax2 - ax1 + 1.0f, eh = ay2 - ay1 + 1.0f;
    const float ecx = ax1 + 0.5f * ew, ecy = ay1 + 0.5f * eh;
    const float gw = gx2 - gx1 + 1.0f, gh = gy2 - gy1 + 1.0f;
    const float gcx = gx1 + 0.5f * gw, gcy = gy1 + 0.5f * gh;
    tg0 = (gcx - ecx) / ew;
    tg1 = (gcy - ecy) / eh;
    tg2 = logf(gw / ew);
    tg3 = logf(gh / eh);
  }
  const float inw = (lab == 1) ? 1.0f : 0.0f;
  const float oww = (lab == 1 || lab == 0) ? uw : 0.0f;

  out[(size_t)b * T_ + i] = (float)lab;
  const size_t ch = ((size_t)b * 36 + (size_t)a * 4) * HW_ + cell;
  float* o1 = out + OUT0_;
  o1[ch] = tg0; o1[ch + HW_] = tg1; o1[ch + 2 * HW_] = tg2; o1[ch + 3 * HW_] = tg3;
  float* o2 = o1 + OUTC_;
  o2[ch] = inw; o2[ch + HW_] = inw; o2[ch + 2 * HW_] = inw; o2[ch + 3 * HW_] = inw;
  float* o3 = o2 + OUTC_;
  o3[ch] = oww; o3[ch + HW_] = oww; o3[ch + 2 * HW_] = oww; o3[ch + 3 * HW_] = oww;
}

extern "C" void kernel_launch(void* const* d_in, const int* in_sizes, int n_in,
                              void* d_out, int out_size, void* d_ws, size_t ws_size,
                              hipStream_t stream) {
  (void)in_sizes; (void)n_in; (void)out_size; (void)ws_size;
  const float* gt = (const float*)d_in[1];   // (32,20,5)
  const float* im = (const float*)d_in[2];   // (32,3)
  float* out = (float*)d_out;

  uint8_t* ws = (uint8_t*)d_ws;
  uint32_t* gmax   = (uint32_t*)(ws + 0);          // 32*32 u32        (4096 B)
  uint32_t* cnt    = (uint32_t*)(ws + 4096);       // 32*2 u32         (256 B)
  uint32_t* sel    = (uint32_t*)(ws + 4352);       // 32*4 u32         (512 B)
  uint32_t* cntblk = (uint32_t*)(ws + 4864);       // 2*32*225 u32     (57600 B)
  int8_t*   labels = (int8_t*)  (ws + 62464);      // 32*57600 i8      (1.84 MB)
  uint32_t* barg   = (uint32_t*)(ws + 1905664);    // 32*57600 u8      (1.84 MB)
  uint32_t* bkey   = (uint32_t*)(ws + 3748864);    // 32*57600 u32     (7.37 MB)
  uint32_t* cand   = (uint32_t*)(ws + 11121664);   // 2*32*57600 u32   (14.7 MB)

  (void)hipMemsetAsync(ws, 0, 4096, stream);  // gmax only (rest fully written)

  k1_iou<<<dim3(75, B_), dim3(192), 0, stream>>>(gt, im, gmax, bkey, barg);
  k2_label<<<dim3(NBLK_, B_), dim3(256), 0, stream>>>(gt, im, gmax, bkey, labels, cntblk, cand);
  k3_select<<<dim3(B_ * 2), dim3(1024), 0, stream>>>(labels, cntblk, cand, cnt, sel);
  k4_final<<<dim3(NBLK_, B_), dim3(256), 0, stream>>>(gt, im, labels, (const int8_t*)barg,
                                                      cnt, sel, out);
}